// Round 11
// baseline (380.616 us; speedup 1.0000x reference)
//
#include <hip/hip_runtime.h>
#include <hip/hip_cooperative_groups.h>
#include <cstdint>

namespace cg = cooperative_groups;

#define NN 1024
#define BB 32
#define LL 128
#define DE 16
#define HH 4
#define K1 4
#define BD 512
#define SLAB 524288   // per-head slab elements (N*BD) for Gt/b2t/b1t

using bf16x8 = __attribute__((ext_vector_type(8))) short;
using f32x4  = __attribute__((ext_vector_type(4))) float;

__device__ inline unsigned short f2bf(float f) {
    unsigned u = __builtin_bit_cast(unsigned, f);
    u += 0x7FFFu + ((u >> 16) & 1u);          // round-to-nearest-even
    return (unsigned short)(u >> 16);
}
__device__ inline float bf2f(unsigned short u) {
    return __builtin_bit_cast(float, (unsigned)u << 16);
}

struct LogitsSmem {
    float ejs[64][17];
    float eis[64][17];
    float kjs[64][64];
    float qis[4][64][17];
    float part[4][5][64];
    float wq[1024];
    float wk[1024];
};
struct XtSmem { float xs[64][128]; };

// ================================================================ PHASE 1
// logits (256) | xt_cast (512) | wtt_cast (16) | zero-out (16) = 800 blocks.
__global__ __launch_bounds__(256) void phase1(
    const float* __restrict__ psi_emb, const float* __restrict__ psi_p,
    const float* __restrict__ W_q, const float* __restrict__ W_k,
    const float* __restrict__ x, const float* __restrict__ F_w,
    short* __restrict__ bnt, short* __restrict__ ant, float* __restrict__ partials,
    short* __restrict__ xt, short* __restrict__ wtt, float* __restrict__ out)
{
    __shared__ __align__(16) char smem_raw[sizeof(LogitsSmem)];
    const int bid = blockIdx.x;
    const int tid = threadIdx.x;

    if (bid < 256) {
        // ---------------- logits role (inline Q/K projection)
        LogitsSmem& S = *(LogitsSmem*)smem_raw;
        const int jb = bid & 15, ib = bid >> 4;
        const int i0 = ib * 64, j0 = jb * 64;
        {
            const int row = tid >> 2, dq = (tid & 3) * 4;
            const float4 vj = *(const float4*)(psi_emb + (j0 + row) * DE + dq);
            S.ejs[row][dq] = vj.x; S.ejs[row][dq + 1] = vj.y;
            S.ejs[row][dq + 2] = vj.z; S.ejs[row][dq + 3] = vj.w;
            const float4 vi = *(const float4*)(psi_emb + (i0 + row) * DE + dq);
            S.eis[row][dq] = vi.x; S.eis[row][dq + 1] = vi.y;
            S.eis[row][dq + 2] = vi.z; S.eis[row][dq + 3] = vi.w;
            *(float4*)&S.wq[tid * 4] = *(const float4*)(W_q + tid * 4);
            *(float4*)&S.wk[tid * 4] = *(const float4*)(W_k + tid * 4);
        }
        __syncthreads();
#pragma unroll
        for (int rep = 0; rep < 16; rep++) {
            const int idx = rep * 256 + tid;
            const int row = idx >> 6, hm = idx & 63;
            float qv = 0.f, kv = 0.f;
#pragma unroll
            for (int d = 0; d < DE; d++) {
                qv += S.eis[row][d] * S.wq[d * 64 + hm];
                kv += S.ejs[row][d] * S.wk[d * 64 + hm];
            }
            S.qis[hm >> 4][row][hm & 15] = qv;
            S.kjs[row][hm] = kv;
        }
        __syncthreads();

        const int i = tid & 63, jg = tid >> 6;
        const float psi = psi_p[0];
        float er[DE];
#pragma unroll
        for (int d = 0; d < DE; d++) er[d] = S.eis[i][d];

        float sb = 0.f, sa[HH] = {0.f, 0.f, 0.f, 0.f};
#pragma unroll
        for (int g = 0; g < 2; g++) {
            unsigned short bw[8];
#pragma unroll
            for (int r = 0; r < 8; r++) {
                const int j = jg * 16 + g * 8 + r;
                float d2 = 0.f;
#pragma unroll
                for (int d = 0; d < DE; d++) { const float t = er[d] - S.ejs[j][d]; d2 += t * t; }
                const float bn = __expf(__expf(-psi * d2));
                sb += bn;
                bw[r] = f2bf(bn);
            }
            uint4 pk;
            pk.x = bw[0] | ((unsigned)bw[1] << 16);
            pk.y = bw[2] | ((unsigned)bw[3] << 16);
            pk.z = bw[4] | ((unsigned)bw[5] << 16);
            pk.w = bw[6] | ((unsigned)bw[7] << 16);
            const size_t toff = (size_t)((j0 + jg * 16 + g * 8) >> 3) * 8192 + (size_t)(i0 + i) * 8;
            *(uint4*)(bnt + toff) = pk;
        }
#pragma unroll
        for (int h = 0; h < HH; h++) {
            float qr[DE];
#pragma unroll
            for (int m = 0; m < DE; m++) qr[m] = S.qis[h][i][m];
#pragma unroll
            for (int g = 0; g < 2; g++) {
                unsigned short aw[8];
#pragma unroll
                for (int r = 0; r < 8; r++) {
                    const int j = jg * 16 + g * 8 + r;
                    float dot = 0.f;
#pragma unroll
                    for (int m = 0; m < DE; m++) dot += qr[m] * S.kjs[j][h * DE + m];
                    const float an = __expf(dot * 0.25f);
                    sa[h] += an;
                    aw[r] = f2bf(an);
                }
                uint4 pk;
                pk.x = aw[0] | ((unsigned)aw[1] << 16);
                pk.y = aw[2] | ((unsigned)aw[3] << 16);
                pk.z = aw[4] | ((unsigned)aw[5] << 16);
                pk.w = aw[6] | ((unsigned)aw[7] << 16);
                const size_t toff = (size_t)((j0 + jg * 16 + g * 8) >> 3) * 8192 + (size_t)(i0 + i) * 8;
                *(uint4*)(ant + (size_t)h * 1048576 + toff) = pk;
            }
        }
        S.part[jg][0][i] = sb;
#pragma unroll
        for (int h = 0; h < HH; h++) S.part[jg][1 + h][i] = sa[h];
        __syncthreads();
        if (tid < 64) {
#pragma unroll
            for (int s = 0; s < 5; s++) {
                const float v = S.part[0][s][tid] + S.part[1][s][tid] +
                                S.part[2][s][tid] + S.part[3][s][tid];
                partials[(size_t)jb * 5120 + (size_t)s * 1024 + i0 + tid] = v;
            }
        }
    } else if (bid < 768) {
        // ---------------- xt_cast role
        XtSmem& X = *(XtSmem*)smem_raw;
        const int idx = bid - 256;
        const int m0 = (idx & 15) * 64;
        const int b  = idx >> 4;
        for (int i = tid; i < 2048; i += 256) {
            const int row = i >> 5, lq = i & 31;
            *(float4*)&X.xs[row][lq * 4] =
                *(const float4*)(x + ((size_t)(b * NN + m0 + row)) * LL + lq * 4);
        }
        __syncthreads();
        for (int j = tid; j < 1024; j += 256) {
            const int m = j & 63, lc = j >> 6;
            const float* s = &X.xs[m][lc * 8];
            uint4 pk;
            pk.x = f2bf(s[0]) | ((unsigned)f2bf(s[1]) << 16);
            pk.y = f2bf(s[2]) | ((unsigned)f2bf(s[3]) << 16);
            pk.z = f2bf(s[4]) | ((unsigned)f2bf(s[5]) << 16);
            pk.w = f2bf(s[6]) | ((unsigned)f2bf(s[7]) << 16);
            *(uint4*)(xt + (size_t)b * 131072 + (size_t)lc * 8192 + (size_t)(m0 + m) * 8) = pk;
        }
    } else if (bid < 784) {
        // ---------------- wtt_cast role
        const int j = (bid - 768) * 256 + tid;
        const int lc = j >> 8, c = j & 255;
        const int h = c >> 6, k = (c >> 4) & 3, d = c & 15;
        const float* s = F_w + (size_t)((h * DE + d) * K1 + k) * LL + lc * 8;
        uint4 pk;
        pk.x = f2bf(s[0]) | ((unsigned)f2bf(s[1]) << 16);
        pk.y = f2bf(s[2]) | ((unsigned)f2bf(s[3]) << 16);
        pk.z = f2bf(s[4]) | ((unsigned)f2bf(s[5]) << 16);
        pk.w = f2bf(s[6]) | ((unsigned)f2bf(s[7]) << 16);
        *(uint4*)(wtt + (size_t)lc * 2048 + (size_t)c * 8) = pk;
    } else {
        // ---------------- zero-out role (out is poisoned 0xAA each launch)
        const int idx = (bid - 784) * 256 + tid;       // 4096 threads, 8 floats each
        const float4 z = {0.f, 0.f, 0.f, 0.f};
        *(float4*)(out + (size_t)idx * 8) = z;
        *(float4*)(out + (size_t)idx * 8 + 4) = z;
    }
}

// ================================================================ PHASE 2
// g_mfma (1024 blocks, all-bf16 tiled Gt output) + blend (256 blocks).
__global__ __launch_bounds__(256) void phase2(
    const short* __restrict__ xt, const short* __restrict__ wtt,
    short* __restrict__ Gt,
    const short* __restrict__ bnt, const short* __restrict__ ant,
    const float* __restrict__ partials, const float* __restrict__ alpha_p,
    short* __restrict__ At)
{
    const int bid = blockIdx.x;
    const int tid = threadIdx.x;
    __shared__ float sums_l[5][64];

    if (bid < 1024) {
        // ---------------- g_mfma role
        const int cb = bid & 3;
        const int m0 = ((bid >> 2) & 15) * 64;
        const int bp = bid >> 6;
        const int wave = tid >> 6, lane = tid & 63;
        const int b  = bp * 2 + (wave >> 1);
        const int wc = wave & 1;
        const int q = lane >> 4, m16 = lane & 15;
        const short* xb = xt + (size_t)b * 131072;

        f32x4 acc[4][2];
#pragma unroll
        for (int mi = 0; mi < 4; mi++)
#pragma unroll
            for (int ni = 0; ni < 2; ni++) acc[mi][ni] = (f32x4){0.f, 0.f, 0.f, 0.f};

#pragma unroll
        for (int ks = 0; ks < 4; ks++) {
            const int kc = ks * 4 + q;
            bf16x8 a[4], bb[2];
#pragma unroll
            for (int mi = 0; mi < 4; mi++)
                a[mi] = *(const bf16x8*)(xb + (size_t)kc * 8192 + (size_t)(m0 + mi * 16 + m16) * 8);
#pragma unroll
            for (int ni = 0; ni < 2; ni++)
                bb[ni] = *(const bf16x8*)(wtt + (size_t)kc * 2048 +
                                          (size_t)(cb * 64 + wc * 32 + ni * 16 + m16) * 8);
#pragma unroll
            for (int mi = 0; mi < 4; mi++)
#pragma unroll
                for (int ni = 0; ni < 2; ni++)
                    acc[mi][ni] = __builtin_amdgcn_mfma_f32_16x16x32_bf16(a[mi], bb[ni], acc[mi][ni], 0, 0, 0);
        }

        // bf16 tiled stores only (full-line coalesced); slab = kk*4+hh
#pragma unroll
        for (int ni = 0; ni < 2; ni++) {
            const int cc = cb * 64 + wc * 32 + ni * 16 + m16;
            const int kk = (cc >> 4) & 3, hh = cc >> 6;
            const int col512 = b * 16 + (cc & 15);
            short* gdst = Gt + (size_t)(kk * 4 + hh) * SLAB;
#pragma unroll
            for (int mi = 0; mi < 4; mi++) {
                const int row0 = m0 + mi * 16 + q * 4;
                ushort4 pk;
                pk.x = f2bf(acc[mi][ni][0]); pk.y = f2bf(acc[mi][ni][1]);
                pk.z = f2bf(acc[mi][ni][2]); pk.w = f2bf(acc[mi][ni][3]);
                *(ushort4*)(gdst + ((size_t)(row0 >> 3) * 512 + col512) * 8 + (row0 & 7)) = pk;
            }
        }
    } else {
        // ---------------- blend role
        const int idx = bid - 1024;
        const int jb = idx & 15, ib = idx >> 4;
        const int i0 = ib * 64, j0 = jb * 64;
        const int lane = tid & 63, w = tid >> 6;
        {
            float acc = 0.f;
#pragma unroll
            for (int jb2 = 0; jb2 < 16; jb2++)
                acc += partials[(size_t)jb2 * 5120 + (size_t)w * 1024 + i0 + lane];
            sums_l[w][lane] = acc;
            if (w == 0) {
                float a4 = 0.f;
#pragma unroll
                for (int jb2 = 0; jb2 < 16; jb2++)
                    a4 += partials[(size_t)jb2 * 5120 + 4 * 1024 + i0 + lane];
                sums_l[4][lane] = a4;
            }
        }
        __syncthreads();
        const int i = lane, jg = w;
        const float alpha = 1.f / (1.f + __expf(-alpha_p[0]));
        const float ibs = alpha / sums_l[0][i];
        float ias[HH];
#pragma unroll
        for (int h = 0; h < HH; h++) ias[h] = (1.f - alpha) / sums_l[1 + h][i];

#pragma unroll
        for (int g = 0; g < 2; g++) {
            const size_t toff = (size_t)((j0 + jg * 16 + g * 8) >> 3) * 8192 + (size_t)(i0 + i) * 8;
            const uint4 bp = *(const uint4*)(bnt + toff);
            float bnv[8];
            bnv[0] = bf2f(bp.x & 0xFFFF); bnv[1] = bf2f(bp.x >> 16);
            bnv[2] = bf2f(bp.y & 0xFFFF); bnv[3] = bf2f(bp.y >> 16);
            bnv[4] = bf2f(bp.z & 0xFFFF); bnv[5] = bf2f(bp.z >> 16);
            bnv[6] = bf2f(bp.w & 0xFFFF); bnv[7] = bf2f(bp.w >> 16);
#pragma unroll
            for (int h = 0; h < HH; h++) {
                const uint4 ap = *(const uint4*)(ant + (size_t)h * 1048576 + toff);
                float av[8];
                av[0] = bf2f(ap.x & 0xFFFF); av[1] = bf2f(ap.x >> 16);
                av[2] = bf2f(ap.y & 0xFFFF); av[3] = bf2f(ap.y >> 16);
                av[4] = bf2f(ap.z & 0xFFFF); av[5] = bf2f(ap.z >> 16);
                av[6] = bf2f(ap.w & 0xFFFF); av[7] = bf2f(ap.w >> 16);
                unsigned short ow[8];
#pragma unroll
                for (int r = 0; r < 8; r++) ow[r] = f2bf(ibs * bnv[r] + ias[h] * av[r]);
                uint4 pk;
                pk.x = ow[0] | ((unsigned)ow[1] << 16);
                pk.y = ow[2] | ((unsigned)ow[3] << 16);
                pk.z = ow[4] | ((unsigned)ow[5] << 16);
                pk.w = ow[6] | ((unsigned)ow[7] << 16);
                *(uint4*)(At + (size_t)h * 1048576 + toff) = pk;
            }
        }
    }
}

// ================================================================ Fused Clenshaw chain (cooperative)
// R10 post-mortem: structural GEMM experiments each return ~4 us; remaining
// controllable cost is launch boundaries + inter-kernel drains on the
// SERIALIZED chain. One cooperative kernel (512 blocks = 2/CU co-resident),
// grid.sync() between stages; A-tile stays L2-hot on its XCD pair across all
// three sub-GEMMs (XCD-affinity swizzle kept from R10).
__device__ inline void k_loop(const short* Ap, const short* Bp, f32x4 acc[2][2]) {
#pragma unroll
    for (int mi = 0; mi < 2; mi++)
#pragma unroll
        for (int ni = 0; ni < 2; ni++) acc[mi][ni] = (f32x4){0.f, 0.f, 0.f, 0.f};
#pragma unroll 8
    for (int it = 0; it < 32; it++) {
        const bf16x8 af0 = *(const bf16x8*)(Ap + (size_t)it * 32768);
        const bf16x8 af1 = *(const bf16x8*)(Ap + (size_t)it * 32768 + 128);
        const bf16x8 bf0 = *(const bf16x8*)(Bp + (size_t)it * 16384);
        const bf16x8 bf1 = *(const bf16x8*)(Bp + (size_t)it * 16384 + 128);
        acc[0][0] = __builtin_amdgcn_mfma_f32_16x16x32_bf16(af0, bf0, acc[0][0], 0, 0, 0);
        acc[0][1] = __builtin_amdgcn_mfma_f32_16x16x32_bf16(af0, bf1, acc[0][1], 0, 0, 0);
        acc[1][0] = __builtin_amdgcn_mfma_f32_16x16x32_bf16(af1, bf0, acc[1][0], 0, 0, 0);
        acc[1][1] = __builtin_amdgcn_mfma_f32_16x16x32_bf16(af1, bf1, acc[1][1], 0, 0, 0);
    }
}

__global__ __launch_bounds__(256) void clenshaw_chain(
    const short* __restrict__ At, const short* __restrict__ Gt,
    short* b2t, short* b1t,
    const float* __restrict__ psi_emb, const float* __restrict__ f_b,
    const float* __restrict__ head_mix, float* __restrict__ out)
{
    cg::grid_group grid = cg::this_grid();

    const int bid = blockIdx.x;                        // 512 blocks, 1D
    const int h = (bid & 7) >> 1;                      // XCD-pair affinity
    const int tile = ((bid >> 3) << 1) | (bid & 1);    // 0..127
    const int c0 = (tile & 7) * 64;
    const int r0 = (tile >> 3) * 64;

    const int tid = threadIdx.x;
    const int wave = tid >> 6, lane = tid & 63;
    const int q = lane >> 4, m16 = lane & 15;
    const int wr = wave >> 1, wc = wave & 1;

    const size_t hs = (size_t)h * SLAB;
    const short* Ap = At + (size_t)h * 1048576 +
                      (size_t)q * 8192 + (size_t)(r0 + wr * 32 + m16) * 8;
    const size_t bofs = (size_t)q * 4096 + (size_t)(c0 + wc * 32 + m16) * 8;

    __shared__ float es[64][17];
    {
        const int row = tid >> 2, dq = (tid & 3) * 4;
        const float4 ev = *(const float4*)(psi_emb + (size_t)(r0 + row) * DE + dq);
        es[row][dq] = ev.x; es[row][dq + 1] = ev.y;
        es[row][dq + 2] = ev.z; es[row][dq + 3] = ev.w;
    }
    __syncthreads();

    f32x4 acc[2][2];

    // ---------------- stage 1: b2t = bf16(G2 + 2*A@G3)
    k_loop(Ap, Gt + (12 + h) * (size_t)SLAB + bofs, acc);
#pragma unroll
    for (int mi = 0; mi < 2; mi++) {
        const int row0 = r0 + wr * 32 + mi * 16 + q * 4;
#pragma unroll
        for (int ni = 0; ni < 2; ni++) {
            const int cc = c0 + wc * 32 + ni * 16 + m16;
            const size_t off = ((size_t)(row0 >> 3) * 512 + cc) * 8 + (row0 & 7);
            const ushort4 pv = *(const ushort4*)(Gt + (8 + h) * (size_t)SLAB + off);
            ushort4 pk;
            pk.x = f2bf(2.f * acc[mi][ni][0] + bf2f(pv.x));
            pk.y = f2bf(2.f * acc[mi][ni][1] + bf2f(pv.y));
            pk.z = f2bf(2.f * acc[mi][ni][2] + bf2f(pv.z));
            pk.w = f2bf(2.f * acc[mi][ni][3] + bf2f(pv.w));
            *(ushort4*)(b2t + hs + off) = pk;
        }
    }
    __threadfence();
    grid.sync();

    // ---------------- stage 2: b1t = bf16(G1 + 2*A@b2 - G3)
    k_loop(Ap, b2t + hs + bofs, acc);
#pragma unroll
    for (int mi = 0; mi < 2; mi++) {
        const int row0 = r0 + wr * 32 + mi * 16 + q * 4;
#pragma unroll
        for (int ni = 0; ni < 2; ni++) {
            const int cc = c0 + wc * 32 + ni * 16 + m16;
            const size_t off = ((size_t)(row0 >> 3) * 512 + cc) * 8 + (row0 & 7);
            const ushort4 pv = *(const ushort4*)(Gt + (4 + h) * (size_t)SLAB + off);
            const ushort4 qv = *(const ushort4*)(Gt + (12 + h) * (size_t)SLAB + off);
            ushort4 pk;
            pk.x = f2bf(2.f * acc[mi][ni][0] + bf2f(pv.x) - bf2f(qv.x));
            pk.y = f2bf(2.f * acc[mi][ni][1] + bf2f(pv.y) - bf2f(qv.y));
            pk.z = f2bf(2.f * acc[mi][ni][2] + bf2f(pv.z) - bf2f(qv.z));
            pk.w = f2bf(2.f * acc[mi][ni][3] + bf2f(pv.w) - bf2f(qv.w));
            *(ushort4*)(b1t + hs + off) = pk;
        }
    }
    __threadfence();
    grid.sync();

    // ---------------- stage 3: out += mw[h] * e·(G0 + A@b1 - b2 + fb)
    k_loop(Ap, b1t + hs + bofs, acc);

    const float hm0 = head_mix[0], hm1 = head_mix[1], hm2 = head_mix[2], hm3 = head_mix[3];
    const float mx = fmaxf(fmaxf(hm0, hm1), fmaxf(hm2, hm3));
    const float w0 = expf(hm0 - mx), w1 = expf(hm1 - mx), w2 = expf(hm2 - mx), w3 = expf(hm3 - mx);
    const float isum = 1.f / (w0 + w1 + w2 + w3);
    const float mwh = (h == 0 ? w0 : h == 1 ? w1 : h == 2 ? w2 : w3) * isum;
    const float fb = f_b[h * DE + m16];

#pragma unroll
    for (int mi = 0; mi < 2; mi++) {
        const int rloc0 = wr * 32 + mi * 16 + q * 4;
        const int row0 = r0 + rloc0;
#pragma unroll
        for (int ni = 0; ni < 2; ni++) {
            const int cc = c0 + wc * 32 + ni * 16 + m16;
            const int b = cc >> 4;
            const size_t off = ((size_t)(row0 >> 3) * 512 + cc) * 8 + (row0 & 7);
            const ushort4 pv = *(const ushort4*)(Gt + (0 + h) * (size_t)SLAB + off);
            const ushort4 qv = *(const ushort4*)(b2t + hs + off);
            float v[4];
            v[0] = acc[mi][ni][0] + bf2f(pv.x) - bf2f(qv.x);
            v[1] = acc[mi][ni][1] + bf2f(pv.y) - bf2f(qv.y);
            v[2] = acc[mi][ni][2] + bf2f(pv.z) - bf2f(qv.z);
            v[3] = acc[mi][ni][3] + bf2f(pv.w) - bf2f(qv.w);
#pragma unroll
            for (int r = 0; r < 4; r++) {
                float w = es[rloc0 + r][m16] * (v[r] + fb);
                w += __shfl_xor(w, 1, 64);
                w += __shfl_xor(w, 2, 64);
                w += __shfl_xor(w, 4, 64);
                w += __shfl_xor(w, 8, 64);
                if (m16 == 0)
                    atomicAdd(out + (size_t)b * NN + (row0 + r), mwh * w);
            }
        }
    }
}

extern "C" void kernel_launch(void* const* d_in, const int* in_sizes, int n_in,
                              void* d_out, int out_size, void* d_ws, size_t ws_size,
                              hipStream_t stream)
{
    const float* x          = (const float*)d_in[0];
    const float* psi_emb    = (const float*)d_in[1];
    const float* psi        = (const float*)d_in[2];
    const float* W_q        = (const float*)d_in[3];
    const float* W_k        = (const float*)d_in[4];
    const float* attn_alpha = (const float*)d_in[5];
    const float* F_w        = (const float*)d_in[6];
    const float* f_b        = (const float*)d_in[7];
    const float* head_mix   = (const float*)d_in[8];
    float* out = (float*)d_out;

    short* At  = (short*)d_ws;                 // 4,194,304 shorts (per-h 1,048,576)
    short* xt  = At + 4194304;                 // 4,194,304
    short* wtt = xt + 4194304;                 // 32,768
    short* Gt  = wtt + 32768;                  // 16 slabs (k*4+h) x 524,288 shorts
    short* b2t = Gt + 8388608;                 // 2,097,152
    short* b1t = b2t + 2097152;                // 2,097,152
    short* bnt = b1t + 2097152;                // 1,048,576
    short* ant = bnt + 1048576;                // 4,194,304
    float* partials = (float*)(ant + 4194304); // 81,920 fp32

    const size_t need_bytes =
        (size_t)(4194304 + 4194304 + 32768 + 8388608 + 2097152 + 2097152 + 1048576 + 4194304) * 2 +
        (size_t)81920 * 4;
    if (ws_size < need_bytes) return;

    phase1<<<800, 256, 0, stream>>>(psi_emb, psi, W_q, W_k, x, F_w,
                                    bnt, ant, partials, xt, wtt, out);
    phase2<<<1280, 256, 0, stream>>>(xt, wtt, Gt, bnt, ant, partials,
                                     attn_alpha, At);

    void* args[] = {(void*)&At, (void*)&Gt, (void*)&b2t, (void*)&b1t,
                    (void*)&psi_emb, (void*)&f_b, (void*)&head_mix, (void*)&out};
    hipLaunchCooperativeKernel((const void*)clenshaw_chain, dim3(512), dim3(256),
                               args, 0, stream);
}

// Round 12
// 149.400 us; speedup vs baseline: 2.5476x; 2.5476x over previous
//
#include <hip/hip_runtime.h>
#include <cstdint>

#define NN 1024
#define BB 32
#define LL 128
#define DE 16
#define HH 4
#define K1 4
#define BD 512
#define NS 524288   // NN*BD elements per head slab

using bf16x8 = __attribute__((ext_vector_type(8))) short;
using f32x4  = __attribute__((ext_vector_type(4))) float;

__device__ inline unsigned short f2bf(float f) {
    unsigned u = __builtin_bit_cast(unsigned, f);
    u += 0x7FFFu + ((u >> 16) & 1u);          // round-to-nearest-even
    return (unsigned short)(u >> 16);
}
__device__ inline float bf2f(unsigned short u) {
    return __builtin_bit_cast(float, (unsigned)u << 16);
}

struct LogitsSmem {
    float ejs[64][17];
    float eis[64][17];
    float kjs[64][64];
    float qis[4][64][17];
    float part[4][5][64];
    float wq[1024];
    float wk[1024];
};
struct XtSmem { float xs[64][128]; };

// ================================================================ PHASE 1
// logits (256) | xt_cast (512) | wtt_cast (16) | zero-out (16) = 800 blocks.
__global__ __launch_bounds__(256) void phase1(
    const float* __restrict__ psi_emb, const float* __restrict__ psi_p,
    const float* __restrict__ W_q, const float* __restrict__ W_k,
    const float* __restrict__ x, const float* __restrict__ F_w,
    short* __restrict__ bnt, short* __restrict__ ant, float* __restrict__ partials,
    short* __restrict__ xt, short* __restrict__ wtt, float* __restrict__ out)
{
    __shared__ __align__(16) char smem_raw[sizeof(LogitsSmem)];
    const int bid = blockIdx.x;
    const int tid = threadIdx.x;

    if (bid < 256) {
        // ---------------- logits role (inline Q/K projection)
        LogitsSmem& S = *(LogitsSmem*)smem_raw;
        const int jb = bid & 15, ib = bid >> 4;
        const int i0 = ib * 64, j0 = jb * 64;
        {
            const int row = tid >> 2, dq = (tid & 3) * 4;
            const float4 vj = *(const float4*)(psi_emb + (j0 + row) * DE + dq);
            S.ejs[row][dq] = vj.x; S.ejs[row][dq + 1] = vj.y;
            S.ejs[row][dq + 2] = vj.z; S.ejs[row][dq + 3] = vj.w;
            const float4 vi = *(const float4*)(psi_emb + (i0 + row) * DE + dq);
            S.eis[row][dq] = vi.x; S.eis[row][dq + 1] = vi.y;
            S.eis[row][dq + 2] = vi.z; S.eis[row][dq + 3] = vi.w;
            *(float4*)&S.wq[tid * 4] = *(const float4*)(W_q + tid * 4);
            *(float4*)&S.wk[tid * 4] = *(const float4*)(W_k + tid * 4);
        }
        __syncthreads();
#pragma unroll
        for (int rep = 0; rep < 16; rep++) {
            const int idx = rep * 256 + tid;
            const int row = idx >> 6, hm = idx & 63;
            float qv = 0.f, kv = 0.f;
#pragma unroll
            for (int d = 0; d < DE; d++) {
                qv += S.eis[row][d] * S.wq[d * 64 + hm];
                kv += S.ejs[row][d] * S.wk[d * 64 + hm];
            }
            S.qis[hm >> 4][row][hm & 15] = qv;
            S.kjs[row][hm] = kv;
        }
        __syncthreads();

        const int i = tid & 63, jg = tid >> 6;
        const float psi = psi_p[0];
        float er[DE];
#pragma unroll
        for (int d = 0; d < DE; d++) er[d] = S.eis[i][d];

        float sb = 0.f, sa[HH] = {0.f, 0.f, 0.f, 0.f};
#pragma unroll
        for (int g = 0; g < 2; g++) {
            unsigned short bw[8];
#pragma unroll
            for (int r = 0; r < 8; r++) {
                const int j = jg * 16 + g * 8 + r;
                float d2 = 0.f;
#pragma unroll
                for (int d = 0; d < DE; d++) { const float t = er[d] - S.ejs[j][d]; d2 += t * t; }
                const float bn = __expf(__expf(-psi * d2));
                sb += bn;
                bw[r] = f2bf(bn);
            }
            uint4 pk;
            pk.x = bw[0] | ((unsigned)bw[1] << 16);
            pk.y = bw[2] | ((unsigned)bw[3] << 16);
            pk.z = bw[4] | ((unsigned)bw[5] << 16);
            pk.w = bw[6] | ((unsigned)bw[7] << 16);
            const size_t toff = (size_t)((j0 + jg * 16 + g * 8) >> 3) * 8192 + (size_t)(i0 + i) * 8;
            *(uint4*)(bnt + toff) = pk;
        }
#pragma unroll
        for (int h = 0; h < HH; h++) {
            float qr[DE];
#pragma unroll
            for (int m = 0; m < DE; m++) qr[m] = S.qis[h][i][m];
#pragma unroll
            for (int g = 0; g < 2; g++) {
                unsigned short aw[8];
#pragma unroll
                for (int r = 0; r < 8; r++) {
                    const int j = jg * 16 + g * 8 + r;
                    float dot = 0.f;
#pragma unroll
                    for (int m = 0; m < DE; m++) dot += qr[m] * S.kjs[j][h * DE + m];
                    const float an = __expf(dot * 0.25f);
                    sa[h] += an;
                    aw[r] = f2bf(an);
                }
                uint4 pk;
                pk.x = aw[0] | ((unsigned)aw[1] << 16);
                pk.y = aw[2] | ((unsigned)aw[3] << 16);
                pk.z = aw[4] | ((unsigned)aw[5] << 16);
                pk.w = aw[6] | ((unsigned)aw[7] << 16);
                const size_t toff = (size_t)((j0 + jg * 16 + g * 8) >> 3) * 8192 + (size_t)(i0 + i) * 8;
                *(uint4*)(ant + (size_t)h * 1048576 + toff) = pk;
            }
        }
        S.part[jg][0][i] = sb;
#pragma unroll
        for (int h = 0; h < HH; h++) S.part[jg][1 + h][i] = sa[h];
        __syncthreads();
        if (tid < 64) {
#pragma unroll
            for (int s = 0; s < 5; s++) {
                const float v = S.part[0][s][tid] + S.part[1][s][tid] +
                                S.part[2][s][tid] + S.part[3][s][tid];
                partials[(size_t)jb * 5120 + (size_t)s * 1024 + i0 + tid] = v;
            }
        }
    } else if (bid < 768) {
        // ---------------- xt_cast role
        XtSmem& X = *(XtSmem*)smem_raw;
        const int idx = bid - 256;
        const int m0 = (idx & 15) * 64;
        const int b  = idx >> 4;
        for (int i = tid; i < 2048; i += 256) {
            const int row = i >> 5, lq = i & 31;
            *(float4*)&X.xs[row][lq * 4] =
                *(const float4*)(x + ((size_t)(b * NN + m0 + row)) * LL + lq * 4);
        }
        __syncthreads();
        for (int j = tid; j < 1024; j += 256) {
            const int m = j & 63, lc = j >> 6;
            const float* s = &X.xs[m][lc * 8];
            uint4 pk;
            pk.x = f2bf(s[0]) | ((unsigned)f2bf(s[1]) << 16);
            pk.y = f2bf(s[2]) | ((unsigned)f2bf(s[3]) << 16);
            pk.z = f2bf(s[4]) | ((unsigned)f2bf(s[5]) << 16);
            pk.w = f2bf(s[6]) | ((unsigned)f2bf(s[7]) << 16);
            *(uint4*)(xt + (size_t)b * 131072 + (size_t)lc * 8192 + (size_t)(m0 + m) * 8) = pk;
        }
    } else if (bid < 784) {
        // ---------------- wtt_cast role
        const int j = (bid - 768) * 256 + tid;
        const int lc = j >> 8, c = j & 255;
        const int h = c >> 6, k = (c >> 4) & 3, d = c & 15;
        const float* s = F_w + (size_t)((h * DE + d) * K1 + k) * LL + lc * 8;
        uint4 pk;
        pk.x = f2bf(s[0]) | ((unsigned)f2bf(s[1]) << 16);
        pk.y = f2bf(s[2]) | ((unsigned)f2bf(s[3]) << 16);
        pk.z = f2bf(s[4]) | ((unsigned)f2bf(s[5]) << 16);
        pk.w = f2bf(s[6]) | ((unsigned)f2bf(s[7]) << 16);
        *(uint4*)(wtt + (size_t)lc * 2048 + (size_t)c * 8) = pk;
    } else {
        // ---------------- zero-out role (out is poisoned 0xAA each launch)
        const int idx = (bid - 784) * 256 + tid;       // 4096 threads, 8 floats each
        const float4 z = {0.f, 0.f, 0.f, 0.f};
        *(float4*)(out + (size_t)idx * 8) = z;
        *(float4*)(out + (size_t)idx * 8 + 4) = z;
    }
}

// ================================================================ PHASE 2
// g_mfma (1024 blocks, all-bf16 tiled Gt output) + blend (256 blocks).
__global__ __launch_bounds__(256) void phase2(
    const short* __restrict__ xt, const short* __restrict__ wtt,
    short* __restrict__ Gt,
    const short* __restrict__ bnt, const short* __restrict__ ant,
    const float* __restrict__ partials, const float* __restrict__ alpha_p,
    short* __restrict__ At)
{
    const int bid = blockIdx.x;
    const int tid = threadIdx.x;
    __shared__ float sums_l[5][64];

    if (bid < 1024) {
        // ---------------- g_mfma role
        const int cb = bid & 3;
        const int m0 = ((bid >> 2) & 15) * 64;
        const int bp = bid >> 6;
        const int wave = tid >> 6, lane = tid & 63;
        const int b  = bp * 2 + (wave >> 1);
        const int wc = wave & 1;
        const int q = lane >> 4, m16 = lane & 15;
        const short* xb = xt + (size_t)b * 131072;

        f32x4 acc[4][2];
#pragma unroll
        for (int mi = 0; mi < 4; mi++)
#pragma unroll
            for (int ni = 0; ni < 2; ni++) acc[mi][ni] = (f32x4){0.f, 0.f, 0.f, 0.f};

#pragma unroll
        for (int ks = 0; ks < 4; ks++) {
            const int kc = ks * 4 + q;
            bf16x8 a[4], bb[2];
#pragma unroll
            for (int mi = 0; mi < 4; mi++)
                a[mi] = *(const bf16x8*)(xb + (size_t)kc * 8192 + (size_t)(m0 + mi * 16 + m16) * 8);
#pragma unroll
            for (int ni = 0; ni < 2; ni++)
                bb[ni] = *(const bf16x8*)(wtt + (size_t)kc * 2048 +
                                          (size_t)(cb * 64 + wc * 32 + ni * 16 + m16) * 8);
#pragma unroll
            for (int mi = 0; mi < 4; mi++)
#pragma unroll
                for (int ni = 0; ni < 2; ni++)
                    acc[mi][ni] = __builtin_amdgcn_mfma_f32_16x16x32_bf16(a[mi], bb[ni], acc[mi][ni], 0, 0, 0);
        }

        // bf16 tiled stores only (full-line coalesced); slab = kk*4+hh
#pragma unroll
        for (int ni = 0; ni < 2; ni++) {
            const int cc = cb * 64 + wc * 32 + ni * 16 + m16;
            const int kk = (cc >> 4) & 3, hh = cc >> 6;
            const int col512 = b * 16 + (cc & 15);
            short* gdst = Gt + (size_t)(kk * 4 + hh) * 524288;
#pragma unroll
            for (int mi = 0; mi < 4; mi++) {
                const int row0 = m0 + mi * 16 + q * 4;
                ushort4 pk;
                pk.x = f2bf(acc[mi][ni][0]); pk.y = f2bf(acc[mi][ni][1]);
                pk.z = f2bf(acc[mi][ni][2]); pk.w = f2bf(acc[mi][ni][3]);
                *(ushort4*)(gdst + ((size_t)(row0 >> 3) * 512 + col512) * 8 + (row0 & 7)) = pk;
            }
        }
    } else {
        // ---------------- blend role
        const int idx = bid - 1024;
        const int jb = idx & 15, ib = idx >> 4;
        const int i0 = ib * 64, j0 = jb * 64;
        const int lane = tid & 63, w = tid >> 6;
        {
            float acc = 0.f;
#pragma unroll
            for (int jb2 = 0; jb2 < 16; jb2++)
                acc += partials[(size_t)jb2 * 5120 + (size_t)w * 1024 + i0 + lane];
            sums_l[w][lane] = acc;
            if (w == 0) {
                float a4 = 0.f;
#pragma unroll
                for (int jb2 = 0; jb2 < 16; jb2++)
                    a4 += partials[(size_t)jb2 * 5120 + 4 * 1024 + i0 + lane];
                sums_l[4][lane] = a4;
            }
        }
        __syncthreads();
        const int i = lane, jg = w;
        const float alpha = 1.f / (1.f + __expf(-alpha_p[0]));
        const float ibs = alpha / sums_l[0][i];
        float ias[HH];
#pragma unroll
        for (int h = 0; h < HH; h++) ias[h] = (1.f - alpha) / sums_l[1 + h][i];

#pragma unroll
        for (int g = 0; g < 2; g++) {
            const size_t toff = (size_t)((j0 + jg * 16 + g * 8) >> 3) * 8192 + (size_t)(i0 + i) * 8;
            const uint4 bp = *(const uint4*)(bnt + toff);
            float bnv[8];
            bnv[0] = bf2f(bp.x & 0xFFFF); bnv[1] = bf2f(bp.x >> 16);
            bnv[2] = bf2f(bp.y & 0xFFFF); bnv[3] = bf2f(bp.y >> 16);
            bnv[4] = bf2f(bp.z & 0xFFFF); bnv[5] = bf2f(bp.z >> 16);
            bnv[6] = bf2f(bp.w & 0xFFFF); bnv[7] = bf2f(bp.w >> 16);
#pragma unroll
            for (int h = 0; h < HH; h++) {
                const uint4 ap = *(const uint4*)(ant + (size_t)h * 1048576 + toff);
                float av[8];
                av[0] = bf2f(ap.x & 0xFFFF); av[1] = bf2f(ap.x >> 16);
                av[2] = bf2f(ap.y & 0xFFFF); av[3] = bf2f(ap.y >> 16);
                av[4] = bf2f(ap.z & 0xFFFF); av[5] = bf2f(ap.z >> 16);
                av[6] = bf2f(ap.w & 0xFFFF); av[7] = bf2f(ap.w >> 16);
                unsigned short ow[8];
#pragma unroll
                for (int r = 0; r < 8; r++) ow[r] = f2bf(ibs * bnv[r] + ias[h] * av[r]);
                uint4 pk;
                pk.x = ow[0] | ((unsigned)ow[1] << 16);
                pk.y = ow[2] | ((unsigned)ow[3] << 16);
                pk.z = ow[4] | ((unsigned)ow[5] << 16);
                pk.w = ow[6] | ((unsigned)ow[7] << 16);
                *(uint4*)(At + (size_t)h * 1048576 + toff) = pk;
            }
        }
    }
}

// ================================================================ Clenshaw GEMM (MFMA, direct-global fragments)
// R11 post-mortem: cooperative grid.sync() cost ~90us/barrier on 8 XCDs
// (clenshaw_chain 260us vs 75us for 3 separate dispatches; MfmaUtil 1.9%).
// On MI355X, back-to-back launches ARE the cheap grid barrier. Keep the
// 3-dispatch chain with XCD-affinity swizzle (bid%8 round-robin -> head pair).
__global__ __launch_bounds__(256) void gemm_mf(
    const short* __restrict__ At, const short* __restrict__ Bt,
    const short* __restrict__ Pt, const short* __restrict__ Qt,
    short* __restrict__ Ot, float scale, float pc, float qc)
{
    const int bid = blockIdx.x;                        // 512 blocks, 1D
    const int h = (bid & 7) >> 1;                      // XCD-pair affinity
    const int tile = ((bid >> 3) << 1) | (bid & 1);    // 0..127
    const int c0 = (tile & 7) * 64;
    const int r0 = (tile >> 3) * 64;

    const short* Ah = At + (size_t)h * 1048576;
    const short* Bh = Bt + (size_t)h * 524288;
    const short* Ph = Pt + (size_t)h * 524288;
    const short* Qh = Qt + (size_t)h * 524288;
    short* Oh = Ot + (size_t)h * 524288;

    const int tid = threadIdx.x;
    const int wave = tid >> 6, lane = tid & 63;
    const int q = lane >> 4, m16 = lane & 15;
    const int wr = wave >> 1, wc = wave & 1;

    const short* Ap = Ah + (size_t)q * 8192 + (size_t)(r0 + wr * 32 + m16) * 8;
    const short* Bp = Bh + (size_t)q * 4096 + (size_t)(c0 + wc * 32 + m16) * 8;

    f32x4 acc[2][2];
#pragma unroll
    for (int mi = 0; mi < 2; mi++)
#pragma unroll
        for (int ni = 0; ni < 2; ni++) acc[mi][ni] = (f32x4){0.f, 0.f, 0.f, 0.f};

#pragma unroll 8
    for (int it = 0; it < 32; it++) {
        const bf16x8 af0 = *(const bf16x8*)(Ap + (size_t)it * 32768);
        const bf16x8 af1 = *(const bf16x8*)(Ap + (size_t)it * 32768 + 128);
        const bf16x8 bf0 = *(const bf16x8*)(Bp + (size_t)it * 16384);
        const bf16x8 bf1 = *(const bf16x8*)(Bp + (size_t)it * 16384 + 128);
        acc[0][0] = __builtin_amdgcn_mfma_f32_16x16x32_bf16(af0, bf0, acc[0][0], 0, 0, 0);
        acc[0][1] = __builtin_amdgcn_mfma_f32_16x16x32_bf16(af0, bf1, acc[0][1], 0, 0, 0);
        acc[1][0] = __builtin_amdgcn_mfma_f32_16x16x32_bf16(af1, bf0, acc[1][0], 0, 0, 0);
        acc[1][1] = __builtin_amdgcn_mfma_f32_16x16x32_bf16(af1, bf1, acc[1][1], 0, 0, 0);
    }

#pragma unroll
    for (int mi = 0; mi < 2; mi++) {
        const int row0 = r0 + wr * 32 + mi * 16 + q * 4;
#pragma unroll
        for (int ni = 0; ni < 2; ni++) {
            const int cc = c0 + wc * 32 + ni * 16 + m16;
            const size_t off = ((size_t)(row0 >> 3) * 512 + cc) * 8 + (row0 & 7);
            const ushort4 pv = *(const ushort4*)(Ph + off);
            float v[4];
            v[0] = scale * acc[mi][ni][0] + pc * bf2f(pv.x);
            v[1] = scale * acc[mi][ni][1] + pc * bf2f(pv.y);
            v[2] = scale * acc[mi][ni][2] + pc * bf2f(pv.z);
            v[3] = scale * acc[mi][ni][3] + pc * bf2f(pv.w);
            if (qc != 0.f) {
                const ushort4 qv = *(const ushort4*)(Qh + off);
                v[0] += qc * bf2f(qv.x); v[1] += qc * bf2f(qv.y);
                v[2] += qc * bf2f(qv.z); v[3] += qc * bf2f(qv.w);
            }
            ushort4 pk;
            pk.x = f2bf(v[0]); pk.y = f2bf(v[1]); pk.z = f2bf(v[2]); pk.w = f2bf(v[3]);
            *(ushort4*)(Oh + off) = pk;
        }
    }
}

// ================================================================ GEMM3 + fused output contraction
__global__ __launch_bounds__(256) void gemm3_out(
    const short* __restrict__ At, const short* __restrict__ Bt,
    const short* __restrict__ Pt, const short* __restrict__ Qt,
    const float* __restrict__ psi_emb, const float* __restrict__ f_b,
    const float* __restrict__ head_mix, float* __restrict__ out)
{
    const int bid = blockIdx.x;                        // 512 blocks, 1D
    const int h = (bid & 7) >> 1;
    const int tile = ((bid >> 3) << 1) | (bid & 1);
    const int c0 = (tile & 7) * 64;
    const int r0 = (tile >> 3) * 64;

    const short* Ah = At + (size_t)h * 1048576;
    const short* Bh = Bt + (size_t)h * 524288;
    const short* Ph = Pt + (size_t)h * 524288;
    const short* Qh = Qt + (size_t)h * 524288;

    const int tid = threadIdx.x;
    const int wave = tid >> 6, lane = tid & 63;
    const int q = lane >> 4, m16 = lane & 15;
    const int wr = wave >> 1, wc = wave & 1;

    __shared__ float es[64][17];
    {
        const int row = tid >> 2, dq = (tid & 3) * 4;
        const float4 ev = *(const float4*)(psi_emb + (size_t)(r0 + row) * DE + dq);
        es[row][dq] = ev.x; es[row][dq + 1] = ev.y;
        es[row][dq + 2] = ev.z; es[row][dq + 3] = ev.w;
    }
    __syncthreads();

    const short* Ap = Ah + (size_t)q * 8192 + (size_t)(r0 + wr * 32 + m16) * 8;
    const short* Bp = Bh + (size_t)q * 4096 + (size_t)(c0 + wc * 32 + m16) * 8;

    f32x4 acc[2][2];
#pragma unroll
    for (int mi = 0; mi < 2; mi++)
#pragma unroll
        for (int ni = 0; ni < 2; ni++) acc[mi][ni] = (f32x4){0.f, 0.f, 0.f, 0.f};

#pragma unroll 8
    for (int it = 0; it < 32; it++) {
        const bf16x8 af0 = *(const bf16x8*)(Ap + (size_t)it * 32768);
        const bf16x8 af1 = *(const bf16x8*)(Ap + (size_t)it * 32768 + 128);
        const bf16x8 bf0 = *(const bf16x8*)(Bp + (size_t)it * 16384);
        const bf16x8 bf1 = *(const bf16x8*)(Bp + (size_t)it * 16384 + 128);
        acc[0][0] = __builtin_amdgcn_mfma_f32_16x16x32_bf16(af0, bf0, acc[0][0], 0, 0, 0);
        acc[0][1] = __builtin_amdgcn_mfma_f32_16x16x32_bf16(af0, bf1, acc[0][1], 0, 0, 0);
        acc[1][0] = __builtin_amdgcn_mfma_f32_16x16x32_bf16(af1, bf0, acc[1][0], 0, 0, 0);
        acc[1][1] = __builtin_amdgcn_mfma_f32_16x16x32_bf16(af1, bf1, acc[1][1], 0, 0, 0);
    }

    const float hm0 = head_mix[0], hm1 = head_mix[1], hm2 = head_mix[2], hm3 = head_mix[3];
    const float mx = fmaxf(fmaxf(hm0, hm1), fmaxf(hm2, hm3));
    const float w0 = expf(hm0 - mx), w1 = expf(hm1 - mx), w2 = expf(hm2 - mx), w3 = expf(hm3 - mx);
    const float isum = 1.f / (w0 + w1 + w2 + w3);
    const float mwh = (h == 0 ? w0 : h == 1 ? w1 : h == 2 ? w2 : w3) * isum;
    const float fb = f_b[h * DE + m16];

#pragma unroll
    for (int mi = 0; mi < 2; mi++) {
        const int rloc0 = wr * 32 + mi * 16 + q * 4;
        const int row0 = r0 + rloc0;
#pragma unroll
        for (int ni = 0; ni < 2; ni++) {
            const int cc = c0 + wc * 32 + ni * 16 + m16;
            const int b = cc >> 4;
            const size_t off = ((size_t)(row0 >> 3) * 512 + cc) * 8 + (row0 & 7);
            const ushort4 pv = *(const ushort4*)(Ph + off);
            const ushort4 qv = *(const ushort4*)(Qh + off);
            float v[4];
            v[0] = acc[mi][ni][0] + bf2f(pv.x) - bf2f(qv.x);
            v[1] = acc[mi][ni][1] + bf2f(pv.y) - bf2f(qv.y);
            v[2] = acc[mi][ni][2] + bf2f(pv.z) - bf2f(qv.z);
            v[3] = acc[mi][ni][3] + bf2f(pv.w) - bf2f(qv.w);
#pragma unroll
            for (int r = 0; r < 4; r++) {
                float w = es[rloc0 + r][m16] * (v[r] + fb);
                w += __shfl_xor(w, 1, 64);
                w += __shfl_xor(w, 2, 64);
                w += __shfl_xor(w, 4, 64);
                w += __shfl_xor(w, 8, 64);
                if (m16 == 0)
                    atomicAdd(out + (size_t)b * NN + (row0 + r), mwh * w);
            }
        }
    }
}

extern "C" void kernel_launch(void* const* d_in, const int* in_sizes, int n_in,
                              void* d_out, int out_size, void* d_ws, size_t ws_size,
                              hipStream_t stream)
{
    const float* x          = (const float*)d_in[0];
    const float* psi_emb    = (const float*)d_in[1];
    const float* psi        = (const float*)d_in[2];
    const float* W_q        = (const float*)d_in[3];
    const float* W_k        = (const float*)d_in[4];
    const float* attn_alpha = (const float*)d_in[5];
    const float* F_w        = (const float*)d_in[6];
    const float* f_b        = (const float*)d_in[7];
    const float* head_mix   = (const float*)d_in[8];
    float* out = (float*)d_out;

    short* At  = (short*)d_ws;                 // 4,194,304 shorts (per-h 1,048,576)
    short* xt  = At + 4194304;                 // 4,194,304
    short* wtt = xt + 4194304;                 // 32,768
    short* Gt  = wtt + 32768;                  // 16 slabs (k*4+h) x 524,288 shorts
    short* b2t = Gt + 8388608;                 // 2,097,152
    short* b1t = b2t + 2097152;                // 2,097,152
    short* bnt = b1t + 2097152;                // 1,048,576
    short* ant = bnt + 1048576;                // 4,194,304
    float* partials = (float*)(ant + 4194304); // 81,920 fp32

    const size_t need_bytes =
        (size_t)(4194304 + 4194304 + 32768 + 8388608 + 2097152 + 2097152 + 1048576 + 4194304) * 2 +
        (size_t)81920 * 4;
    if (ws_size < need_bytes) return;

    phase1<<<800, 256, 0, stream>>>(psi_emb, psi, W_q, W_k, x, F_w,
                                    bnt, ant, partials, xt, wtt, out);
    phase2<<<1280, 256, 0, stream>>>(xt, wtt, Gt, bnt, ant, partials,
                                     attn_alpha, At);

    // b2t = bf16(G2 + 2*A@G3)
    gemm_mf<<<512, 256, 0, stream>>>(At, Gt + 12 * (size_t)524288, Gt + 8 * (size_t)524288,
                                     Gt /*unused*/, b2t, 2.f, 1.f, 0.f);
    // b1t = bf16(G1 + 2*A@b2 - G3)
    gemm_mf<<<512, 256, 0, stream>>>(At, b2t, Gt + 4 * (size_t)524288,
                                     Gt + 12 * (size_t)524288, b1t, 2.f, 1.f, -1.f);
    // out += mw[h] * e·(G0 + A@b1 - b2 + fb)
    gemm3_out<<<512, 256, 0, stream>>>(At, b1t, Gt, b2t, psi_emb, f_b, head_mix, out);
}